// Round 4
// baseline (447.075 us; speedup 1.0000x reference)
//
#include <hip/hip_runtime.h>
#include <stdint.h>
#include <math.h>

// Problem: B=4, S=2048, E=1024, H=16, D=64
// d_in order (setup_inputs dict): x, Wk, Wq, Wv, Wu, bu   (note Wk before Wq!)

typedef __attribute__((ext_vector_type(8))) short bf16x8;
typedef __attribute__((ext_vector_type(4))) float f32x4;
typedef __attribute__((ext_vector_type(16))) float f32x16;
typedef __attribute__((ext_vector_type(4))) int i32x4;
typedef __attribute__((ext_vector_type(4))) short s16x4;

#define GLOAD_LDS16(gp, lp)                                                     \
  __builtin_amdgcn_global_load_lds(                                             \
      (__attribute__((address_space(1))) void*)(gp),                            \
      (__attribute__((address_space(3))) void*)(lp), 16, 0, 0)

__device__ __forceinline__ short f2bf(float f) {
  union { float f; uint32_t u; } v; v.f = f;
  uint32_t r = v.u + 0x7FFFu + ((v.u >> 16) & 1u);  // RNE
  return (short)(r >> 16);
}
__device__ __forceinline__ float bf2f(short s) {
  union { uint32_t u; float f; } v; v.u = ((uint32_t)(uint16_t)s) << 16;
  return v.f;
}
// native converts (compiler pairs into v_cvt_pk_bf16_f32)
__device__ __forceinline__ short f2bfn(float f) {
  union { __bf16 h; short s; } u; u.h = (__bf16)f; return u.s;
}
__device__ __forceinline__ uint32_t pk2n(float a, float b) {
  union { __bf16 h[2]; uint32_t u; } v;
  v.h[0] = (__bf16)a; v.h[1] = (__bf16)b;
  return v.u;
}

// exchange across the lane<32 / lane>=32 split (T12)
__device__ __forceinline__ void swap32(uint32_t a, uint32_t b, int hi,
                                       uint32_t& out0, uint32_t& out1) {
#if __has_builtin(__builtin_amdgcn_permlane32_swap)
  typedef __attribute__((ext_vector_type(2))) int i32x2;
  i32x2 r = __builtin_amdgcn_permlane32_swap((int)a, (int)b, false, false);
  out0 = (uint32_t)r.x; out1 = (uint32_t)r.y;
#else
  uint32_t ta = (uint32_t)__shfl_xor((int)a, 32);
  uint32_t tb = (uint32_t)__shfl_xor((int)b, 32);
  out0 = hi ? tb : a;
  out1 = hi ? b : ta;
#endif
}

// ---------------- cast fp32 -> bf16, vectorized (G13) ----------------
__global__ __launch_bounds__(256) void cast_kernel(const float* __restrict__ src,
                                                   short* __restrict__ dst, int n) {
  int i = (blockIdx.x * 256 + threadIdx.x) * 8;
  if (i >= n) return;
  const float4* s = (const float4*)(src + i);
  float4 f0 = s[0], f1 = s[1];
  bf16x8 o;
  o[0] = f2bf(f0.x); o[1] = f2bf(f0.y); o[2] = f2bf(f0.z); o[3] = f2bf(f0.w);
  o[4] = f2bf(f1.x); o[5] = f2bf(f1.y); o[6] = f2bf(f1.z); o[7] = f2bf(f1.w);
  *(bf16x8*)(dst + i) = o;
}

__global__ __launch_bounds__(256) void cast4_kernel(const float* __restrict__ w0,
                                                    const float* __restrict__ w1,
                                                    const float* __restrict__ w2,
                                                    const float* __restrict__ w3,
                                                    short* o0, short* o1, short* o2, short* o3) {
  const float* src = (blockIdx.y == 0) ? w0 : (blockIdx.y == 1) ? w1 : (blockIdx.y == 2) ? w2 : w3;
  short* dst = (blockIdx.y == 0) ? o0 : (blockIdx.y == 1) ? o1 : (blockIdx.y == 2) ? o2 : o3;
  int i = (blockIdx.x * 256 + threadIdx.x) * 8;
  const float4* s = (const float4*)(src + i);
  float4 f0 = s[0], f1 = s[1];
  bf16x8 o;
  o[0] = f2bf(f0.x); o[1] = f2bf(f0.y); o[2] = f2bf(f0.z); o[3] = f2bf(f0.w);
  o[4] = f2bf(f1.x); o[5] = f2bf(f1.y); o[6] = f2bf(f1.z); o[7] = f2bf(f1.w);
  *(bf16x8*)(dst + i) = o;
}

// ---------------- B^T GEMM (m97 structure): C[i,j] = sum_k A[i,k]*B[j,k] ----
template <bool F32OUT>
__device__ __forceinline__ void gemm_bt_core(const short* __restrict__ A,
                                             const short* __restrict__ Bm,
                                             short* __restrict__ Cb,
                                             float* __restrict__ Cf,
                                             const float* __restrict__ bias) {
  __shared__ short a_lds[128 * 64];
  __shared__ short b_lds[128 * 64];
  const int tid = threadIdx.x;
  const int w = tid >> 6, l = tid & 63;
  const int l15 = l & 15, lhi = l >> 4;
  const int wr = w >> 1, wc = w & 1;
  const int row0 = blockIdx.x * 128;
  const int col0 = blockIdx.y * 128;

  f32x4 acc[4][4];
#pragma unroll
  for (int m = 0; m < 4; ++m)
#pragma unroll
    for (int n = 0; n < 4; ++n)
      acc[m][n] = (f32x4){0.f, 0.f, 0.f, 0.f};

  const int o0 = tid * 16;
  const int sr = o0 >> 7;
  const int sc = o0 & 127;

  for (int kt = 0; kt < 16; ++kt) {
    const char* Ab = (const char*)A + (size_t)(row0 + sr) * 2048 + kt * 128 + sc;
    const char* Bb = (const char*)Bm + (size_t)(col0 + sr) * 2048 + kt * 128 + sc;
#pragma unroll
    for (int i = 0; i < 4; ++i) {
      GLOAD_LDS16(Ab + (size_t)i * 32 * 2048, (char*)a_lds + i * 4096 + o0);
      GLOAD_LDS16(Bb + (size_t)i * 32 * 2048, (char*)b_lds + i * 4096 + o0);
    }
    __syncthreads();
#pragma unroll
    for (int kk = 0; kk < 2; ++kk) {
      bf16x8 af[4], bg[4];
#pragma unroll
      for (int m = 0; m < 4; ++m) {
        int r = wr * 64 + m * 16 + l15;
        af[m] = *(const bf16x8*)((const char*)a_lds + r * 128 + kk * 64 + lhi * 16);
      }
#pragma unroll
      for (int n = 0; n < 4; ++n) {
        int r = wc * 64 + n * 16 + l15;
        bg[n] = *(const bf16x8*)((const char*)b_lds + r * 128 + kk * 64 + lhi * 16);
      }
#pragma unroll
      for (int m = 0; m < 4; ++m)
#pragma unroll
        for (int n = 0; n < 4; ++n)
          acc[m][n] = __builtin_amdgcn_mfma_f32_16x16x32_bf16(af[m], bg[n], acc[m][n], 0, 0, 0);
    }
    __syncthreads();
  }

#pragma unroll
  for (int m = 0; m < 4; ++m) {
#pragma unroll
    for (int n = 0; n < 4; ++n) {
      int colg = col0 + wc * 64 + n * 16 + l15;
#pragma unroll
      for (int r = 0; r < 4; ++r) {
        int rowg = row0 + wr * 64 + m * 16 + lhi * 4 + r;
        float v = acc[m][n][r];
        if constexpr (F32OUT) {
          Cf[(size_t)rowg * 1024 + colg] = v + bias[colg];
        } else {
          Cb[(size_t)rowg * 1024 + colg] = f2bfn(v);
        }
      }
    }
  }
}

__global__ __launch_bounds__(256) void gemm_qkv_kernel(const short* __restrict__ xb,
                                                       const short* __restrict__ wq,
                                                       const short* __restrict__ wk,
                                                       const short* __restrict__ wv,
                                                       short* qo, short* ko, short* vo) {
  const short* Bm = (blockIdx.z == 0) ? wq : (blockIdx.z == 1) ? wk : wv;
  short* C = (blockIdx.z == 0) ? qo : (blockIdx.z == 1) ? ko : vo;
  gemm_bt_core<false>(xb, Bm, C, nullptr, nullptr);
}

__global__ __launch_bounds__(256) void gemm_out_kernel(const short* __restrict__ ob,
                                                       const short* __restrict__ wu,
                                                       const float* __restrict__ bias,
                                                       float* __restrict__ out) {
  gemm_bt_core<true>(ob, wu, nullptr, out, bias);
}

// ---------------- V transpose: v[b,s,h,d] -> vt[(b*16+h)*64+d][s] ----------------
__global__ __launch_bounds__(256) void transpose_v_kernel(const short* __restrict__ vb,
                                                          short* __restrict__ vt) {
  int st = blockIdx.x, bh = blockIdx.y;
  int b = bh >> 4, h = bh & 15;
  __shared__ short tile[64][66];
  int tid = threadIdx.x;
  int sl = tid >> 2;
  int d0 = (tid & 3) * 16;
  const short* src = vb + (size_t)(b * 2048 + st * 64 + sl) * 1024 + h * 64 + d0;
  bf16x8 v0 = *(const bf16x8*)(src);
  bf16x8 v1 = *(const bf16x8*)(src + 8);
#pragma unroll
  for (int i = 0; i < 8; ++i) tile[d0 + i][sl] = v0[i];
#pragma unroll
  for (int i = 0; i < 8; ++i) tile[d0 + 8 + i][sl] = v1[i];
  __syncthreads();
  int d = tid >> 2;
  int s0 = (tid & 3) * 16;
  bf16x8 o0, o1;
#pragma unroll
  for (int i = 0; i < 8; ++i) o0[i] = tile[d][s0 + i];
#pragma unroll
  for (int i = 0; i < 8; ++i) o1[i] = tile[d][s0 + 8 + i];
  short* dst = vt + (size_t)(bh * 64 + d) * 2048 + st * 64 + s0;
  *(bf16x8*)dst = o0;
  *(bf16x8*)(dst + 8) = o1;
}

// ---------------- causal flash attention v4: k-split + LDS merge ----------------
// grid (bh=64, pg=8) x 512 thr (8 waves). Waves (ws, ws+4) split the k-range of
// balanced strip-pair (i, 63-i); merge partial (O, m, l) through LDS.
// All 8 blocks of one bh land on one XCD (linear id % 8 == bh % 8) -> K/V L2-resident.
__global__ __launch_bounds__(512, 4) void attn_kernel(const short* __restrict__ qb,
                                                      const short* __restrict__ kb,
                                                      const short* __restrict__ vt,
                                                      short* __restrict__ ob) {
  const float QSCALE = 0.03125f * 1.44269504f;  // (E^-0.25)^2 * log2(e)
  const float THR = 11.5416f;                   // 8 * log2(e)
  int bh = blockIdx.x, pg = blockIdx.y;
  int b = bh >> 4, h = bh & 15;
  int wid = threadIdx.x >> 6, l = threadIdx.x & 63;
  int l31 = l & 31, hi = l >> 5;
  int ws = wid & 3, half = wid >> 2;
  int i = pg * 4 + ws;  // pair index 0..31

  __shared__ float mlds[4][64][35];  // [pair-slot][lane][o_lo16, o_hi16, m, l] (+pad)

  const short* kstrip = kb + ((size_t)b * 2048 + l31) * 1024 + h * 64 + hi * 8;
  const short* vlo = vt + ((size_t)bh * 64 + l31) * 2048 + hi * 8;
  const short* vhi = vlo + 32 * 2048;

#pragma unroll
  for (int part = 0; part < 2; ++part) {
    int strip = part ? (63 - i) : i;
    int qrow0 = strip * 32;
    int qg = qrow0 + l31;
    const short* qbase = qb + ((size_t)(b * 2048 + qg)) * 1024 + h * 64 + hi * 8;
    bf16x8 aq[4];
#pragma unroll
    for (int s = 0; s < 4; ++s) {
      bf16x8 t = *(const bf16x8*)(qbase + s * 16);
#pragma unroll
      for (int j = 0; j < 8; ++j) t[j] = f2bfn(bf2f(t[j]) * QSCALE);
      aq[s] = t;
    }

    f32x16 o_lo = {}, o_hi = {};
    float mr = -INFINITY, lsum = 0.f;
    int nd = (strip + 2) >> 1;           // dual(64k)-iterations for this strip
    int t0 = half ? (nd >> 1) : 0;
    int t1 = half ? nd : (nd >> 1);

    if (t0 < t1) {
      bf16x8 kc[8];
      {
        const short* kp = kstrip + (size_t)(t0 * 64) * 1024;
#pragma unroll
        for (int s = 0; s < 4; ++s) {
          kc[s]     = *(const bf16x8*)(kp + s * 16);
          kc[4 + s] = *(const bf16x8*)(kp + (size_t)32 * 1024 + s * 16);
        }
      }

      for (int t = t0; t < t1; ++t) {
        int k0 = t * 64;
        f32x16 st0 = {}, st1 = {};
#pragma unroll
        for (int s = 0; s < 4; ++s)
          st0 = __builtin_amdgcn_mfma_f32_32x32x16_bf16(kc[s], aq[s], st0, 0, 0, 0);
#pragma unroll
        for (int s = 0; s < 4; ++s)
          st1 = __builtin_amdgcn_mfma_f32_32x32x16_bf16(kc[4 + s], aq[s], st1, 0, 0, 0);

        // prefetch next K directly into kc (clamped addr; unused values on last iter)
        {
          int kpn = (t + 1 < t1) ? (t + 1) * 64 : t0 * 64;
          const short* kp = kstrip + (size_t)kpn * 1024;
#pragma unroll
          for (int s = 0; s < 4; ++s) {
            kc[s]     = *(const bf16x8*)(kp + s * 16);
            kc[4 + s] = *(const bf16x8*)(kp + (size_t)32 * 1024 + s * 16);
          }
        }
        // V loads issued before softmax; consumed after
        bf16x8 vc[8];
#pragma unroll
        for (int ks = 0; ks < 4; ++ks) {
          vc[ks]     = *(const bf16x8*)(vlo + k0 + ks * 16);
          vc[4 + ks] = *(const bf16x8*)(vhi + k0 + ks * 16);
        }

        if (k0 + 31 > qrow0) {
#pragma unroll
          for (int r = 0; r < 16; ++r) {
            int kk = k0 + (r & 3) + 8 * (r >> 2) + 4 * hi;
            if (kk > qg) st0[r] = -INFINITY;
          }
        }
        if (k0 + 63 > qrow0) {
#pragma unroll
          for (int r = 0; r < 16; ++r) {
            int kk = k0 + 32 + (r & 3) + 8 * (r >> 2) + 4 * hi;
            if (kk > qg) st1[r] = -INFINITY;
          }
        }

        // max tree (depth 5)
        float mx[16];
#pragma unroll
        for (int r = 0; r < 16; ++r) mx[r] = fmaxf(st0[r], st1[r]);
#pragma unroll
        for (int r = 0; r < 8; ++r) mx[r] = fmaxf(mx[r], mx[r + 8]);
#pragma unroll
        for (int r = 0; r < 4; ++r) mx[r] = fmaxf(mx[r], mx[r + 4]);
        float pmax = fmaxf(fmaxf(mx[0], mx[1]), fmaxf(mx[2], mx[3]));
        pmax = fmaxf(pmax, __shfl_xor(pmax, 32));

        if (pmax > mr + THR) {  // T13 defer-max
          float alpha = exp2f(mr - pmax);
          mr = pmax;
          lsum *= alpha;
#pragma unroll
          for (int r = 0; r < 16; ++r) { o_lo[r] *= alpha; o_hi[r] *= alpha; }
        }

#pragma unroll
        for (int r = 0; r < 16; ++r) st0[r] = exp2f(st0[r] - mr);
#pragma unroll
        for (int r = 0; r < 16; ++r) st1[r] = exp2f(st1[r] - mr);
        // sum tree (depth 5)
        float sm[16];
#pragma unroll
        for (int r = 0; r < 16; ++r) sm[r] = st0[r] + st1[r];
#pragma unroll
        for (int r = 0; r < 8; ++r) sm[r] += sm[r + 8];
#pragma unroll
        for (int r = 0; r < 4; ++r) sm[r] += sm[r + 4];
        lsum += (sm[0] + sm[1]) + (sm[2] + sm[3]);

        // T12 pack: P -> bf16 A-fragments
        uint32_t a0, a2, b1, b3, c0, c2, d1, d3;
        swap32(pk2n(st0[0], st0[1]),   pk2n(st0[4], st0[5]),   hi, a0, a2);
        swap32(pk2n(st0[2], st0[3]),   pk2n(st0[6], st0[7]),   hi, b1, b3);
        swap32(pk2n(st0[8], st0[9]),   pk2n(st0[12], st0[13]), hi, c0, c2);
        swap32(pk2n(st0[10], st0[11]), pk2n(st0[14], st0[15]), hi, d1, d3);
        i32x4 u0 = {(int)a0, (int)b1, (int)a2, (int)b3};
        i32x4 u1 = {(int)c0, (int)d1, (int)c2, (int)d3};
        swap32(pk2n(st1[0], st1[1]),   pk2n(st1[4], st1[5]),   hi, a0, a2);
        swap32(pk2n(st1[2], st1[3]),   pk2n(st1[6], st1[7]),   hi, b1, b3);
        swap32(pk2n(st1[8], st1[9]),   pk2n(st1[12], st1[13]), hi, c0, c2);
        swap32(pk2n(st1[10], st1[11]), pk2n(st1[14], st1[15]), hi, d1, d3);
        i32x4 u2 = {(int)a0, (int)b1, (int)a2, (int)b3};
        i32x4 u3 = {(int)c0, (int)d1, (int)c2, (int)d3};
        bf16x8 pa0 = __builtin_bit_cast(bf16x8, u0);
        bf16x8 pa1 = __builtin_bit_cast(bf16x8, u1);
        bf16x8 pa2 = __builtin_bit_cast(bf16x8, u2);
        bf16x8 pa3 = __builtin_bit_cast(bf16x8, u3);

        o_lo = __builtin_amdgcn_mfma_f32_32x32x16_bf16(vc[0], pa0, o_lo, 0, 0, 0);
        o_hi = __builtin_amdgcn_mfma_f32_32x32x16_bf16(vc[4], pa0, o_hi, 0, 0, 0);
        o_lo = __builtin_amdgcn_mfma_f32_32x32x16_bf16(vc[1], pa1, o_lo, 0, 0, 0);
        o_hi = __builtin_amdgcn_mfma_f32_32x32x16_bf16(vc[5], pa1, o_hi, 0, 0, 0);
        o_lo = __builtin_amdgcn_mfma_f32_32x32x16_bf16(vc[2], pa2, o_lo, 0, 0, 0);
        o_hi = __builtin_amdgcn_mfma_f32_32x32x16_bf16(vc[6], pa2, o_hi, 0, 0, 0);
        o_lo = __builtin_amdgcn_mfma_f32_32x32x16_bf16(vc[3], pa3, o_lo, 0, 0, 0);
        o_hi = __builtin_amdgcn_mfma_f32_32x32x16_bf16(vc[7], pa3, o_hi, 0, 0, 0);
      }
    }

    lsum += __shfl_xor(lsum, 32);  // row-total for this k-half

    __syncthreads();
    if (half == 1) {
      float* pp = &mlds[ws][l][0];
#pragma unroll
      for (int r = 0; r < 16; ++r) { pp[r] = o_lo[r]; pp[16 + r] = o_hi[r]; }
      pp[32] = mr; pp[33] = lsum;
    }
    __syncthreads();
    if (half == 0) {
      const float* pp = &mlds[ws][l][0];
      float m1 = pp[32], l1 = pp[33];
      float mn = fmaxf(mr, m1);
      float a0 = exp2f(mr - mn), a1 = exp2f(m1 - mn);
      float inv = 1.0f / (lsum * a0 + l1 * a1);
      short* obase = ob + (size_t)(b * 2048 + qg) * 1024 + h * 64;
#pragma unroll
      for (int g = 0; g < 4; ++g) {
        int d0 = 8 * g + 4 * hi;
        s16x4 v0, v1;
#pragma unroll
        for (int j = 0; j < 4; ++j) {
          v0[j] = f2bfn((o_lo[4 * g + j] * a0 + pp[4 * g + j] * a1) * inv);
          v1[j] = f2bfn((o_hi[4 * g + j] * a0 + pp[16 + 4 * g + j] * a1) * inv);
        }
        *(s16x4*)(obase + d0) = v0;
        *(s16x4*)(obase + 32 + d0) = v1;
      }
    }
  }
}

extern "C" void kernel_launch(void* const* d_in, const int* in_sizes, int n_in,
                              void* d_out, int out_size, void* d_ws, size_t ws_size,
                              hipStream_t stream) {
  const float* x  = (const float*)d_in[0];
  const float* Wk = (const float*)d_in[1];
  const float* Wq = (const float*)d_in[2];
  const float* Wv = (const float*)d_in[3];
  const float* Wu = (const float*)d_in[4];
  const float* bu = (const float*)d_in[5];
  float* out = (float*)d_out;

  char* ws = (char*)d_ws;
  const size_t MB = 1u << 20;
  short* xb  = (short*)(ws + 0 * MB);
  short* qb  = (short*)(ws + 16 * MB);
  short* kb  = (short*)(ws + 32 * MB);
  short* vb  = (short*)(ws + 48 * MB);
  short* vtb = (short*)(ws + 64 * MB);
  short* ob  = (short*)(ws + 80 * MB);
  short* wqb = (short*)(ws + 96 * MB);
  short* wkb = (short*)(ws + 98 * MB);
  short* wvb = (short*)(ws + 100 * MB);
  short* wub = (short*)(ws + 102 * MB);

  cast_kernel<<<4096, 256, 0, stream>>>(x, xb, 8388608);
  cast4_kernel<<<dim3(512, 4), 256, 0, stream>>>(Wq, Wk, Wv, Wu, wqb, wkb, wvb, wub);

  gemm_qkv_kernel<<<dim3(64, 8, 3), 256, 0, stream>>>(xb, wqb, wkb, wvb, qb, kb, vb);
  transpose_v_kernel<<<dim3(32, 64), 256, 0, stream>>>(vb, vtb);
  attn_kernel<<<dim3(64, 8), 512, 0, stream>>>(qb, kb, vtb, ob);
  gemm_out_kernel<<<dim3(64, 8), 256, 0, stream>>>(ob, wub, bu, out);
}

// Round 5
// 251.244 us; speedup vs baseline: 1.7794x; 1.7794x over previous
//
#include <hip/hip_runtime.h>
#include <stdint.h>
#include <math.h>

// Problem: B=4, S=2048, E=1024, H=16, D=64
// d_in order (setup_inputs dict): x, Wk, Wq, Wv, Wu, bu   (note Wk before Wq!)

typedef __attribute__((ext_vector_type(8))) short bf16x8;
typedef __attribute__((ext_vector_type(4))) float f32x4;
typedef __attribute__((ext_vector_type(16))) float f32x16;
typedef __attribute__((ext_vector_type(4))) int i32x4;
typedef __attribute__((ext_vector_type(4))) short s16x4;

#define GLOAD_LDS16(gp, lp)                                                     \
  __builtin_amdgcn_global_load_lds(                                             \
      (__attribute__((address_space(1))) void*)(gp),                            \
      (__attribute__((address_space(3))) void*)(lp), 16, 0, 0)

__device__ __forceinline__ short f2bf(float f) {
  union { float f; uint32_t u; } v; v.f = f;
  uint32_t r = v.u + 0x7FFFu + ((v.u >> 16) & 1u);  // RNE
  return (short)(r >> 16);
}
__device__ __forceinline__ float bf2f(short s) {
  union { uint32_t u; float f; } v; v.u = ((uint32_t)(uint16_t)s) << 16;
  return v.f;
}
// native converts (compiler pairs into v_cvt_pk_bf16_f32)
__device__ __forceinline__ short f2bfn(float f) {
  union { __bf16 h; short s; } u; u.h = (__bf16)f; return u.s;
}
__device__ __forceinline__ uint32_t pk2n(float a, float b) {
  union { __bf16 h[2]; uint32_t u; } v;
  v.h[0] = (__bf16)a; v.h[1] = (__bf16)b;
  return v.u;
}

// exchange across the lane<32 / lane>=32 split (T12)
__device__ __forceinline__ void swap32(uint32_t a, uint32_t b, int hi,
                                       uint32_t& out0, uint32_t& out1) {
#if __has_builtin(__builtin_amdgcn_permlane32_swap)
  typedef __attribute__((ext_vector_type(2))) int i32x2;
  i32x2 r = __builtin_amdgcn_permlane32_swap((int)a, (int)b, false, false);
  out0 = (uint32_t)r.x; out1 = (uint32_t)r.y;
#else
  uint32_t ta = (uint32_t)__shfl_xor((int)a, 32);
  uint32_t tb = (uint32_t)__shfl_xor((int)b, 32);
  out0 = hi ? tb : a;
  out1 = hi ? b : ta;
#endif
}

// ---------------- cast fp32 -> bf16, vectorized (G13) ----------------
__global__ __launch_bounds__(256) void cast_kernel(const float* __restrict__ src,
                                                   short* __restrict__ dst, int n) {
  int i = (blockIdx.x * 256 + threadIdx.x) * 8;
  if (i >= n) return;
  const float4* s = (const float4*)(src + i);
  float4 f0 = s[0], f1 = s[1];
  bf16x8 o;
  o[0] = f2bf(f0.x); o[1] = f2bf(f0.y); o[2] = f2bf(f0.z); o[3] = f2bf(f0.w);
  o[4] = f2bf(f1.x); o[5] = f2bf(f1.y); o[6] = f2bf(f1.z); o[7] = f2bf(f1.w);
  *(bf16x8*)(dst + i) = o;
}

__global__ __launch_bounds__(256) void cast4_kernel(const float* __restrict__ w0,
                                                    const float* __restrict__ w1,
                                                    const float* __restrict__ w2,
                                                    const float* __restrict__ w3,
                                                    short* o0, short* o1, short* o2, short* o3) {
  const float* src = (blockIdx.y == 0) ? w0 : (blockIdx.y == 1) ? w1 : (blockIdx.y == 2) ? w2 : w3;
  short* dst = (blockIdx.y == 0) ? o0 : (blockIdx.y == 1) ? o1 : (blockIdx.y == 2) ? o2 : o3;
  int i = (blockIdx.x * 256 + threadIdx.x) * 8;
  const float4* s = (const float4*)(src + i);
  float4 f0 = s[0], f1 = s[1];
  bf16x8 o;
  o[0] = f2bf(f0.x); o[1] = f2bf(f0.y); o[2] = f2bf(f0.z); o[3] = f2bf(f0.w);
  o[4] = f2bf(f1.x); o[5] = f2bf(f1.y); o[6] = f2bf(f1.z); o[7] = f2bf(f1.w);
  *(bf16x8*)(dst + i) = o;
}

// ---------------- B^T GEMM (m97 structure): C[i,j] = sum_k A[i,k]*B[j,k] ----
template <bool F32OUT>
__device__ __forceinline__ void gemm_bt_core(const short* __restrict__ A,
                                             const short* __restrict__ Bm,
                                             short* __restrict__ Cb,
                                             float* __restrict__ Cf,
                                             const float* __restrict__ bias) {
  __shared__ short a_lds[128 * 64];
  __shared__ short b_lds[128 * 64];
  const int tid = threadIdx.x;
  const int w = tid >> 6, l = tid & 63;
  const int l15 = l & 15, lhi = l >> 4;
  const int wr = w >> 1, wc = w & 1;
  const int row0 = blockIdx.x * 128;
  const int col0 = blockIdx.y * 128;

  f32x4 acc[4][4];
#pragma unroll
  for (int m = 0; m < 4; ++m)
#pragma unroll
    for (int n = 0; n < 4; ++n)
      acc[m][n] = (f32x4){0.f, 0.f, 0.f, 0.f};

  const int o0 = tid * 16;
  const int sr = o0 >> 7;
  const int sc = o0 & 127;

  for (int kt = 0; kt < 16; ++kt) {
    const char* Ab = (const char*)A + (size_t)(row0 + sr) * 2048 + kt * 128 + sc;
    const char* Bb = (const char*)Bm + (size_t)(col0 + sr) * 2048 + kt * 128 + sc;
#pragma unroll
    for (int i = 0; i < 4; ++i) {
      GLOAD_LDS16(Ab + (size_t)i * 32 * 2048, (char*)a_lds + i * 4096 + o0);
      GLOAD_LDS16(Bb + (size_t)i * 32 * 2048, (char*)b_lds + i * 4096 + o0);
    }
    __syncthreads();
#pragma unroll
    for (int kk = 0; kk < 2; ++kk) {
      bf16x8 af[4], bg[4];
#pragma unroll
      for (int m = 0; m < 4; ++m) {
        int r = wr * 64 + m * 16 + l15;
        af[m] = *(const bf16x8*)((const char*)a_lds + r * 128 + kk * 64 + lhi * 16);
      }
#pragma unroll
      for (int n = 0; n < 4; ++n) {
        int r = wc * 64 + n * 16 + l15;
        bg[n] = *(const bf16x8*)((const char*)b_lds + r * 128 + kk * 64 + lhi * 16);
      }
#pragma unroll
      for (int m = 0; m < 4; ++m)
#pragma unroll
        for (int n = 0; n < 4; ++n)
          acc[m][n] = __builtin_amdgcn_mfma_f32_16x16x32_bf16(af[m], bg[n], acc[m][n], 0, 0, 0);
    }
    __syncthreads();
  }

#pragma unroll
  for (int m = 0; m < 4; ++m) {
#pragma unroll
    for (int n = 0; n < 4; ++n) {
      int colg = col0 + wc * 64 + n * 16 + l15;
#pragma unroll
      for (int r = 0; r < 4; ++r) {
        int rowg = row0 + wr * 64 + m * 16 + lhi * 4 + r;
        float v = acc[m][n][r];
        if constexpr (F32OUT) {
          Cf[(size_t)rowg * 1024 + colg] = v + bias[colg];
        } else {
          Cb[(size_t)rowg * 1024 + colg] = f2bfn(v);
        }
      }
    }
  }
}

__global__ __launch_bounds__(256) void gemm_qkv_kernel(const short* __restrict__ xb,
                                                       const short* __restrict__ wq,
                                                       const short* __restrict__ wk,
                                                       const short* __restrict__ wv,
                                                       short* qo, short* ko, short* vo) {
  const short* Bm = (blockIdx.z == 0) ? wq : (blockIdx.z == 1) ? wk : wv;
  short* C = (blockIdx.z == 0) ? qo : (blockIdx.z == 1) ? ko : vo;
  gemm_bt_core<false>(xb, Bm, C, nullptr, nullptr);
}

__global__ __launch_bounds__(256) void gemm_out_kernel(const short* __restrict__ ob,
                                                       const short* __restrict__ wu,
                                                       const float* __restrict__ bias,
                                                       float* __restrict__ out) {
  gemm_bt_core<true>(ob, wu, nullptr, out, bias);
}

// ---------------- V transpose: v[b,s,h,d] -> vt[(b*16+h)*64+d][s] ----------------
__global__ __launch_bounds__(256) void transpose_v_kernel(const short* __restrict__ vb,
                                                          short* __restrict__ vt) {
  int st = blockIdx.x, bh = blockIdx.y;
  int b = bh >> 4, h = bh & 15;
  __shared__ short tile[64][66];
  int tid = threadIdx.x;
  int sl = tid >> 2;
  int d0 = (tid & 3) * 16;
  const short* src = vb + (size_t)(b * 2048 + st * 64 + sl) * 1024 + h * 64 + d0;
  bf16x8 v0 = *(const bf16x8*)(src);
  bf16x8 v1 = *(const bf16x8*)(src + 8);
#pragma unroll
  for (int i = 0; i < 8; ++i) tile[d0 + i][sl] = v0[i];
#pragma unroll
  for (int i = 0; i < 8; ++i) tile[d0 + 8 + i][sl] = v1[i];
  __syncthreads();
  int d = tid >> 2;
  int s0 = (tid & 3) * 16;
  bf16x8 o0, o1;
#pragma unroll
  for (int i = 0; i < 8; ++i) o0[i] = tile[d][s0 + i];
#pragma unroll
  for (int i = 0; i < 8; ++i) o1[i] = tile[d][s0 + 8 + i];
  short* dst = vt + (size_t)(bh * 64 + d) * 2048 + st * 64 + s0;
  *(bf16x8*)dst = o0;
  *(bf16x8*)(dst + 8) = o1;
}

// ---------------- causal flash attention v5: k-split, no launch-bounds cap ---
// grid (bh=64, pg=8) x 512 thr (8 waves). Waves (ws, ws+4) split the k-range of
// balanced strip-pair (i, 63-i); merge partial (O, m, l) through LDS.
// V loads split into two 4-reg batches to keep peak liveness < 128 VGPR.
__global__ __launch_bounds__(512) void attn_kernel(const short* __restrict__ qb,
                                                   const short* __restrict__ kb,
                                                   const short* __restrict__ vt,
                                                   short* __restrict__ ob) {
  const float QSCALE = 0.03125f * 1.44269504f;  // (E^-0.25)^2 * log2(e)
  const float THR = 11.5416f;                   // 8 * log2(e)
  int bh = blockIdx.x, pg = blockIdx.y;
  int b = bh >> 4, h = bh & 15;
  int wid = threadIdx.x >> 6, l = threadIdx.x & 63;
  int l31 = l & 31, hi = l >> 5;
  int ws = wid & 3, half = wid >> 2;
  int i = pg * 4 + ws;  // pair index 0..31

  __shared__ float mlds[4][64][35];  // [pair-slot][lane][o_lo16, o_hi16, m, l] (+pad)

  const short* kstrip = kb + ((size_t)b * 2048 + l31) * 1024 + h * 64 + hi * 8;
  const short* vlo = vt + ((size_t)bh * 64 + l31) * 2048 + hi * 8;
  const short* vhi = vlo + 32 * 2048;

#pragma unroll
  for (int part = 0; part < 2; ++part) {
    int strip = part ? (63 - i) : i;
    int qrow0 = strip * 32;
    int qg = qrow0 + l31;
    const short* qbase = qb + ((size_t)(b * 2048 + qg)) * 1024 + h * 64 + hi * 8;
    bf16x8 aq[4];
#pragma unroll
    for (int s = 0; s < 4; ++s) {
      bf16x8 t = *(const bf16x8*)(qbase + s * 16);
#pragma unroll
      for (int j = 0; j < 8; ++j) t[j] = f2bfn(bf2f(t[j]) * QSCALE);
      aq[s] = t;
    }

    f32x16 o_lo = {}, o_hi = {};
    float mr = -INFINITY, lsum = 0.f;
    int nd = (strip + 2) >> 1;           // dual(64k)-iterations for this strip
    int t0 = half ? (nd >> 1) : 0;
    int t1 = half ? nd : (nd >> 1);

    if (t0 < t1) {
      bf16x8 kc[8];
      {
        const short* kp = kstrip + (size_t)(t0 * 64) * 1024;
#pragma unroll
        for (int s = 0; s < 4; ++s) {
          kc[s]     = *(const bf16x8*)(kp + s * 16);
          kc[4 + s] = *(const bf16x8*)(kp + (size_t)32 * 1024 + s * 16);
        }
      }

      for (int t = t0; t < t1; ++t) {
        int k0 = t * 64;
        f32x16 st0 = {}, st1 = {};
#pragma unroll
        for (int s = 0; s < 4; ++s)
          st0 = __builtin_amdgcn_mfma_f32_32x32x16_bf16(kc[s], aq[s], st0, 0, 0, 0);
#pragma unroll
        for (int s = 0; s < 4; ++s)
          st1 = __builtin_amdgcn_mfma_f32_32x32x16_bf16(kc[4 + s], aq[s], st1, 0, 0, 0);

        // prefetch next K directly into kc (clamped addr; unused values on last iter)
        {
          int kpn = (t + 1 < t1) ? (t + 1) * 64 : t0 * 64;
          const short* kp = kstrip + (size_t)kpn * 1024;
#pragma unroll
          for (int s = 0; s < 4; ++s) {
            kc[s]     = *(const bf16x8*)(kp + s * 16);
            kc[4 + s] = *(const bf16x8*)(kp + (size_t)32 * 1024 + s * 16);
          }
        }
        // V batch a: ks 0,1 issued before softmax (hide L2 latency under VALU)
        bf16x8 va0, va1, va2, va3;
        va0 = *(const bf16x8*)(vlo + k0);
        va1 = *(const bf16x8*)(vhi + k0);
        va2 = *(const bf16x8*)(vlo + k0 + 16);
        va3 = *(const bf16x8*)(vhi + k0 + 16);

        if (k0 + 31 > qrow0) {
#pragma unroll
          for (int r = 0; r < 16; ++r) {
            int kk = k0 + (r & 3) + 8 * (r >> 2) + 4 * hi;
            if (kk > qg) st0[r] = -INFINITY;
          }
        }
        if (k0 + 63 > qrow0) {
#pragma unroll
          for (int r = 0; r < 16; ++r) {
            int kk = k0 + 32 + (r & 3) + 8 * (r >> 2) + 4 * hi;
            if (kk > qg) st1[r] = -INFINITY;
          }
        }

        // max tree (depth 5)
        float mx[16];
#pragma unroll
        for (int r = 0; r < 16; ++r) mx[r] = fmaxf(st0[r], st1[r]);
#pragma unroll
        for (int r = 0; r < 8; ++r) mx[r] = fmaxf(mx[r], mx[r + 8]);
#pragma unroll
        for (int r = 0; r < 4; ++r) mx[r] = fmaxf(mx[r], mx[r + 4]);
        float pmax = fmaxf(fmaxf(mx[0], mx[1]), fmaxf(mx[2], mx[3]));
        pmax = fmaxf(pmax, __shfl_xor(pmax, 32));

        if (pmax > mr + THR) {  // T13 defer-max
          float alpha = exp2f(mr - pmax);
          mr = pmax;
          lsum *= alpha;
#pragma unroll
          for (int r = 0; r < 16; ++r) { o_lo[r] *= alpha; o_hi[r] *= alpha; }
        }

#pragma unroll
        for (int r = 0; r < 16; ++r) st0[r] = exp2f(st0[r] - mr);
#pragma unroll
        for (int r = 0; r < 16; ++r) st1[r] = exp2f(st1[r] - mr);
        // sum tree (depth 5)
        float sm[16];
#pragma unroll
        for (int r = 0; r < 16; ++r) sm[r] = st0[r] + st1[r];
#pragma unroll
        for (int r = 0; r < 8; ++r) sm[r] += sm[r + 8];
#pragma unroll
        for (int r = 0; r < 4; ++r) sm[r] += sm[r + 4];
        lsum += (sm[0] + sm[1]) + (sm[2] + sm[3]);

        // T12 pack: P -> bf16 A-fragments (st regs die here)
        uint32_t a0, a2, b1, b3, c0, c2, d1, d3;
        swap32(pk2n(st0[0], st0[1]),   pk2n(st0[4], st0[5]),   hi, a0, a2);
        swap32(pk2n(st0[2], st0[3]),   pk2n(st0[6], st0[7]),   hi, b1, b3);
        swap32(pk2n(st0[8], st0[9]),   pk2n(st0[12], st0[13]), hi, c0, c2);
        swap32(pk2n(st0[10], st0[11]), pk2n(st0[14], st0[15]), hi, d1, d3);
        i32x4 u0 = {(int)a0, (int)b1, (int)a2, (int)b3};
        i32x4 u1 = {(int)c0, (int)d1, (int)c2, (int)d3};
        swap32(pk2n(st1[0], st1[1]),   pk2n(st1[4], st1[5]),   hi, a0, a2);
        swap32(pk2n(st1[2], st1[3]),   pk2n(st1[6], st1[7]),   hi, b1, b3);
        swap32(pk2n(st1[8], st1[9]),   pk2n(st1[12], st1[13]), hi, c0, c2);
        swap32(pk2n(st1[10], st1[11]), pk2n(st1[14], st1[15]), hi, d1, d3);
        i32x4 u2 = {(int)a0, (int)b1, (int)a2, (int)b3};
        i32x4 u3 = {(int)c0, (int)d1, (int)c2, (int)d3};
        bf16x8 pa0 = __builtin_bit_cast(bf16x8, u0);
        bf16x8 pa1 = __builtin_bit_cast(bf16x8, u1);
        bf16x8 pa2 = __builtin_bit_cast(bf16x8, u2);
        bf16x8 pa3 = __builtin_bit_cast(bf16x8, u3);

        // V batch b issued now (st regs dead -> low peak liveness)
        bf16x8 vb0, vb1, vb2, vb3;
        vb0 = *(const bf16x8*)(vlo + k0 + 32);
        vb1 = *(const bf16x8*)(vhi + k0 + 32);
        vb2 = *(const bf16x8*)(vlo + k0 + 48);
        vb3 = *(const bf16x8*)(vhi + k0 + 48);

        o_lo = __builtin_amdgcn_mfma_f32_32x32x16_bf16(va0, pa0, o_lo, 0, 0, 0);
        o_hi = __builtin_amdgcn_mfma_f32_32x32x16_bf16(va1, pa0, o_hi, 0, 0, 0);
        o_lo = __builtin_amdgcn_mfma_f32_32x32x16_bf16(va2, pa1, o_lo, 0, 0, 0);
        o_hi = __builtin_amdgcn_mfma_f32_32x32x16_bf16(va3, pa1, o_hi, 0, 0, 0);
        o_lo = __builtin_amdgcn_mfma_f32_32x32x16_bf16(vb0, pa2, o_lo, 0, 0, 0);
        o_hi = __builtin_amdgcn_mfma_f32_32x32x16_bf16(vb1, pa2, o_hi, 0, 0, 0);
        o_lo = __builtin_amdgcn_mfma_f32_32x32x16_bf16(vb2, pa3, o_lo, 0, 0, 0);
        o_hi = __builtin_amdgcn_mfma_f32_32x32x16_bf16(vb3, pa3, o_hi, 0, 0, 0);
      }
    }

    lsum += __shfl_xor(lsum, 32);  // row-total for this k-half

    __syncthreads();
    if (half == 1) {
      float* pp = &mlds[ws][l][0];
#pragma unroll
      for (int r = 0; r < 16; ++r) { pp[r] = o_lo[r]; pp[16 + r] = o_hi[r]; }
      pp[32] = mr; pp[33] = lsum;
    }
    __syncthreads();
    if (half == 0) {
      const float* pp = &mlds[ws][l][0];
      float m1 = pp[32], l1 = pp[33];
      float mn = fmaxf(mr, m1);
      float a0 = exp2f(mr - mn), a1 = exp2f(m1 - mn);
      float inv = 1.0f / (lsum * a0 + l1 * a1);
      short* obase = ob + (size_t)(b * 2048 + qg) * 1024 + h * 64;
#pragma unroll
      for (int g = 0; g < 4; ++g) {
        int d0 = 8 * g + 4 * hi;
        s16x4 v0, v1;
#pragma unroll
        for (int j = 0; j < 4; ++j) {
          v0[j] = f2bfn((o_lo[4 * g + j] * a0 + pp[4 * g + j] * a1) * inv);
          v1[j] = f2bfn((o_hi[4 * g + j] * a0 + pp[16 + 4 * g + j] * a1) * inv);
        }
        *(s16x4*)(obase + d0) = v0;
        *(s16x4*)(obase + 32 + d0) = v1;
      }
    }
  }
}

extern "C" void kernel_launch(void* const* d_in, const int* in_sizes, int n_in,
                              void* d_out, int out_size, void* d_ws, size_t ws_size,
                              hipStream_t stream) {
  const float* x  = (const float*)d_in[0];
  const float* Wk = (const float*)d_in[1];
  const float* Wq = (const float*)d_in[2];
  const float* Wv = (const float*)d_in[3];
  const float* Wu = (const float*)d_in[4];
  const float* bu = (const float*)d_in[5];
  float* out = (float*)d_out;

  char* ws = (char*)d_ws;
  const size_t MB = 1u << 20;
  short* xb  = (short*)(ws + 0 * MB);
  short* qb  = (short*)(ws + 16 * MB);
  short* kb  = (short*)(ws + 32 * MB);
  short* vb  = (short*)(ws + 48 * MB);
  short* vtb = (short*)(ws + 64 * MB);
  short* ob  = (short*)(ws + 80 * MB);
  short* wqb = (short*)(ws + 96 * MB);
  short* wkb = (short*)(ws + 98 * MB);
  short* wvb = (short*)(ws + 100 * MB);
  short* wub = (short*)(ws + 102 * MB);

  cast_kernel<<<4096, 256, 0, stream>>>(x, xb, 8388608);
  cast4_kernel<<<dim3(512, 4), 256, 0, stream>>>(Wq, Wk, Wv, Wu, wqb, wkb, wvb, wub);

  gemm_qkv_kernel<<<dim3(64, 8, 3), 256, 0, stream>>>(xb, wqb, wkb, wvb, qb, kb, vb);
  transpose_v_kernel<<<dim3(32, 64), 256, 0, stream>>>(vb, vtb);
  attn_kernel<<<dim3(64, 8), 512, 0, stream>>>(qb, kb, vtb, ob);
  gemm_out_kernel<<<dim3(64, 8), 256, 0, stream>>>(ob, wub, bu, out);
}

// Round 6
// 193.877 us; speedup vs baseline: 2.3060x; 1.2959x over previous
//
#include <hip/hip_runtime.h>
#include <stdint.h>
#include <math.h>

// Problem: B=4, S=2048, E=1024, H=16, D=64
// d_in order (setup_inputs dict): x, Wk, Wq, Wv, Wu, bu   (note Wk before Wq!)

typedef __attribute__((ext_vector_type(8))) short bf16x8;
typedef __attribute__((ext_vector_type(4))) float f32x4;
typedef __attribute__((ext_vector_type(16))) float f32x16;
typedef __attribute__((ext_vector_type(4))) int i32x4;
typedef __attribute__((ext_vector_type(4))) short s16x4;

#define GLOAD_LDS16(gp, lp)                                                     \
  __builtin_amdgcn_global_load_lds(                                             \
      (__attribute__((address_space(1))) void*)(gp),                            \
      (__attribute__((address_space(3))) void*)(lp), 16, 0, 0)

__device__ __forceinline__ short f2bf(float f) {
  union { float f; uint32_t u; } v; v.f = f;
  uint32_t r = v.u + 0x7FFFu + ((v.u >> 16) & 1u);  // RNE
  return (short)(r >> 16);
}
__device__ __forceinline__ float bf2f(short s) {
  union { uint32_t u; float f; } v; v.u = ((uint32_t)(uint16_t)s) << 16;
  return v.f;
}
// native converts (compiler pairs into v_cvt_pk_bf16_f32)
__device__ __forceinline__ short f2bfn(float f) {
  union { __bf16 h; short s; } u; u.h = (__bf16)f; return u.s;
}
__device__ __forceinline__ uint32_t pk2n(float a, float b) {
  union { __bf16 h[2]; uint32_t u; } v;
  v.h[0] = (__bf16)a; v.h[1] = (__bf16)b;
  return v.u;
}

// exchange across the lane<32 / lane>=32 split (T12)
__device__ __forceinline__ void swap32(uint32_t a, uint32_t b, int hi,
                                       uint32_t& out0, uint32_t& out1) {
#if __has_builtin(__builtin_amdgcn_permlane32_swap)
  typedef __attribute__((ext_vector_type(2))) int i32x2;
  i32x2 r = __builtin_amdgcn_permlane32_swap((int)a, (int)b, false, false);
  out0 = (uint32_t)r.x; out1 = (uint32_t)r.y;
#else
  uint32_t ta = (uint32_t)__shfl_xor((int)a, 32);
  uint32_t tb = (uint32_t)__shfl_xor((int)b, 32);
  out0 = hi ? tb : a;
  out1 = hi ? b : ta;
#endif
}

// ---------------- cast fp32 -> bf16, vectorized (G13) ----------------
__global__ __launch_bounds__(256) void cast_kernel(const float* __restrict__ src,
                                                   short* __restrict__ dst, int n) {
  int i = (blockIdx.x * 256 + threadIdx.x) * 8;
  if (i >= n) return;
  const float4* s = (const float4*)(src + i);
  float4 f0 = s[0], f1 = s[1];
  bf16x8 o;
  o[0] = f2bf(f0.x); o[1] = f2bf(f0.y); o[2] = f2bf(f0.z); o[3] = f2bf(f0.w);
  o[4] = f2bf(f1.x); o[5] = f2bf(f1.y); o[6] = f2bf(f1.z); o[7] = f2bf(f1.w);
  *(bf16x8*)(dst + i) = o;
}

__global__ __launch_bounds__(256) void cast4_kernel(const float* __restrict__ w0,
                                                    const float* __restrict__ w1,
                                                    const float* __restrict__ w2,
                                                    const float* __restrict__ w3,
                                                    short* o0, short* o1, short* o2, short* o3) {
  const float* src = (blockIdx.y == 0) ? w0 : (blockIdx.y == 1) ? w1 : (blockIdx.y == 2) ? w2 : w3;
  short* dst = (blockIdx.y == 0) ? o0 : (blockIdx.y == 1) ? o1 : (blockIdx.y == 2) ? o2 : o3;
  int i = (blockIdx.x * 256 + threadIdx.x) * 8;
  const float4* s = (const float4*)(src + i);
  float4 f0 = s[0], f1 = s[1];
  bf16x8 o;
  o[0] = f2bf(f0.x); o[1] = f2bf(f0.y); o[2] = f2bf(f0.z); o[3] = f2bf(f0.w);
  o[4] = f2bf(f1.x); o[5] = f2bf(f1.y); o[6] = f2bf(f1.z); o[7] = f2bf(f1.w);
  *(bf16x8*)(dst + i) = o;
}

// ---------------- B^T GEMM (m97 structure): C[i,j] = sum_k A[i,k]*B[j,k] ----
template <bool F32OUT>
__device__ __forceinline__ void gemm_bt_core(const short* __restrict__ A,
                                             const short* __restrict__ Bm,
                                             short* __restrict__ Cb,
                                             float* __restrict__ Cf,
                                             const float* __restrict__ bias) {
  __shared__ short a_lds[128 * 64];
  __shared__ short b_lds[128 * 64];
  const int tid = threadIdx.x;
  const int w = tid >> 6, l = tid & 63;
  const int l15 = l & 15, lhi = l >> 4;
  const int wr = w >> 1, wc = w & 1;
  const int row0 = blockIdx.x * 128;
  const int col0 = blockIdx.y * 128;

  f32x4 acc[4][4];
#pragma unroll
  for (int m = 0; m < 4; ++m)
#pragma unroll
    for (int n = 0; n < 4; ++n)
      acc[m][n] = (f32x4){0.f, 0.f, 0.f, 0.f};

  const int o0 = tid * 16;
  const int sr = o0 >> 7;
  const int sc = o0 & 127;

  for (int kt = 0; kt < 16; ++kt) {
    const char* Ab = (const char*)A + (size_t)(row0 + sr) * 2048 + kt * 128 + sc;
    const char* Bb = (const char*)Bm + (size_t)(col0 + sr) * 2048 + kt * 128 + sc;
#pragma unroll
    for (int i = 0; i < 4; ++i) {
      GLOAD_LDS16(Ab + (size_t)i * 32 * 2048, (char*)a_lds + i * 4096 + o0);
      GLOAD_LDS16(Bb + (size_t)i * 32 * 2048, (char*)b_lds + i * 4096 + o0);
    }
    __syncthreads();
#pragma unroll
    for (int kk = 0; kk < 2; ++kk) {
      bf16x8 af[4], bg[4];
#pragma unroll
      for (int m = 0; m < 4; ++m) {
        int r = wr * 64 + m * 16 + l15;
        af[m] = *(const bf16x8*)((const char*)a_lds + r * 128 + kk * 64 + lhi * 16);
      }
#pragma unroll
      for (int n = 0; n < 4; ++n) {
        int r = wc * 64 + n * 16 + l15;
        bg[n] = *(const bf16x8*)((const char*)b_lds + r * 128 + kk * 64 + lhi * 16);
      }
#pragma unroll
      for (int m = 0; m < 4; ++m)
#pragma unroll
        for (int n = 0; n < 4; ++n)
          acc[m][n] = __builtin_amdgcn_mfma_f32_16x16x32_bf16(af[m], bg[n], acc[m][n], 0, 0, 0);
    }
    __syncthreads();
  }

#pragma unroll
  for (int m = 0; m < 4; ++m) {
#pragma unroll
    for (int n = 0; n < 4; ++n) {
      int colg = col0 + wc * 64 + n * 16 + l15;
#pragma unroll
      for (int r = 0; r < 4; ++r) {
        int rowg = row0 + wr * 64 + m * 16 + lhi * 4 + r;
        float v = acc[m][n][r];
        if constexpr (F32OUT) {
          Cf[(size_t)rowg * 1024 + colg] = v + bias[colg];
        } else {
          Cb[(size_t)rowg * 1024 + colg] = f2bfn(v);
        }
      }
    }
  }
}

__global__ __launch_bounds__(256) void gemm_qkv_kernel(const short* __restrict__ xb,
                                                       const short* __restrict__ wq,
                                                       const short* __restrict__ wk,
                                                       const short* __restrict__ wv,
                                                       short* qo, short* ko, short* vo) {
  const short* Bm = (blockIdx.z == 0) ? wq : (blockIdx.z == 1) ? wk : wv;
  short* C = (blockIdx.z == 0) ? qo : (blockIdx.z == 1) ? ko : vo;
  gemm_bt_core<false>(xb, Bm, C, nullptr, nullptr);
}

__global__ __launch_bounds__(256) void gemm_out_kernel(const short* __restrict__ ob,
                                                       const short* __restrict__ wu,
                                                       const float* __restrict__ bias,
                                                       float* __restrict__ out) {
  gemm_bt_core<true>(ob, wu, nullptr, out, bias);
}

// ---------------- V transpose: v[b,s,h,d] -> vt[(b*16+h)*64+d][s] ----------------
__global__ __launch_bounds__(256) void transpose_v_kernel(const short* __restrict__ vb,
                                                          short* __restrict__ vt) {
  int st = blockIdx.x, bh = blockIdx.y;
  int b = bh >> 4, h = bh & 15;
  __shared__ short tile[64][66];
  int tid = threadIdx.x;
  int sl = tid >> 2;
  int d0 = (tid & 3) * 16;
  const short* src = vb + (size_t)(b * 2048 + st * 64 + sl) * 1024 + h * 64 + d0;
  bf16x8 v0 = *(const bf16x8*)(src);
  bf16x8 v1 = *(const bf16x8*)(src + 8);
#pragma unroll
  for (int i = 0; i < 8; ++i) tile[d0 + i][sl] = v0[i];
#pragma unroll
  for (int i = 0; i < 8; ++i) tile[d0 + 8 + i][sl] = v1[i];
  __syncthreads();
  int d = tid >> 2;
  int s0 = (tid & 3) * 16;
  bf16x8 o0, o1;
#pragma unroll
  for (int i = 0; i < 8; ++i) o0[i] = tile[d][s0 + i];
#pragma unroll
  for (int i = 0; i < 8; ++i) o1[i] = tile[d][s0 + 8 + i];
  short* dst = vt + (size_t)(bh * 64 + d) * 2048 + st * 64 + s0;
  *(bf16x8*)dst = o0;
  *(bf16x8*)(dst + 8) = o1;
}

// ---------------- causal flash attention v6: LDS-staged K/V, XOR-swizzled ---
// grid 512 blocks (largest-first), 512 thr (8 waves). Block = 256 q-rows
// (q-tile T = 7 - id/64, bh = id&63), wave w owns rows Q0+32w..+31.
// Per 64-k tile: K(8KB)+V^T(8KB) staged via global_load_lds (coalesced,
// pre-swizzled source), double-buffered; ds_read_b128 with T2 XOR swizzle.
__global__ __launch_bounds__(512) void attn_kernel(const short* __restrict__ qb,
                                                   const short* __restrict__ kb,
                                                   const short* __restrict__ vt,
                                                   short* __restrict__ ob) {
  const float QSCALE = 0.03125f * 1.44269504f;  // (E^-0.25)^2 * log2(e)
  const float THR = 11.5416f;                   // 8 * log2(e)
  int id = blockIdx.x;
  int T = 7 - (id >> 6);       // largest-first launch order
  int bh = id & 63;            // id%8 == bh%8 -> all blocks of a bh on one XCD
  int b = bh >> 4, h = bh & 15;
  int wid = threadIdx.x >> 6, l = threadIdx.x & 63;
  int l31 = l & 31, hi = l >> 5;
  int Q0 = T * 256;
  int nk = 4 * (T + 1);
  int qrow0 = Q0 + wid * 32;
  int qg = qrow0 + l31;
  int qmax = qrow0 + 31;

  __shared__ short kv_lds[2][2][64 * 64];  // [buf][K|V][64 rows x 128B], 32 KB

  // staging slot: linear LDS byte o; logical col = sc ^ ((row&7)<<4) (involution)
  int tid = threadIdx.x;
  int o = tid * 16;
  int sr = o >> 7;
  int sc0 = (o & 127) ^ ((sr & 7) << 4);
  const short* Ksrc0 = kb + ((size_t)b * 2048 + sr) * 1024 + h * 64 + (sc0 >> 1);
  const short* Vsrc0 = vt + ((size_t)bh * 64 + sr) * 2048 + (sc0 >> 1);

  // Q fragments, pre-scaled
  const short* qbase = qb + ((size_t)(b * 2048 + qg)) * 1024 + h * 64 + hi * 8;
  bf16x8 aq[4];
#pragma unroll
  for (int s = 0; s < 4; ++s) {
    bf16x8 t = *(const bf16x8*)(qbase + s * 16);
#pragma unroll
    for (int j = 0; j < 8; ++j) t[j] = f2bfn(bf2f(t[j]) * QSCALE);
    aq[s] = t;
  }

  f32x16 o_lo = {}, o_hi = {};
  float mr = -INFINITY, lsum = 0.f;

  // prologue: stage tile 0 into buf 0
  GLOAD_LDS16(Ksrc0, (char*)&kv_lds[0][0][0] + o);
  GLOAD_LDS16(Vsrc0, (char*)&kv_lds[0][1][0] + o);
  __syncthreads();

  const int swz = (l31 & 7) << 4;
  for (int kt = 0; kt < nk; ++kt) {
    int k0 = kt * 64;
    int cur = kt & 1;
    if (kt + 1 < nk) {  // stage next tile into the other buffer
      GLOAD_LDS16(Ksrc0 + (size_t)(k0 + 64) * 1024, (char*)&kv_lds[cur ^ 1][0][0] + o);
      GLOAD_LDS16(Vsrc0 + (k0 + 64), (char*)&kv_lds[cur ^ 1][1][0] + o);
    }
    if (k0 <= qmax) {  // wave-uniform causal skip
      const char* kbase = (const char*)&kv_lds[cur][0][0];
      const char* vbase = (const char*)&kv_lds[cur][1][0];
      f32x16 st0 = {}, st1 = {};
      {
        int rb = l31 * 128;
#pragma unroll
        for (int s = 0; s < 4; ++s) {
          bf16x8 ak = *(const bf16x8*)(kbase + rb + ((s * 32 + hi * 16) ^ swz));
          st0 = __builtin_amdgcn_mfma_f32_32x32x16_bf16(ak, aq[s], st0, 0, 0, 0);
        }
        rb = (l31 + 32) * 128;
#pragma unroll
        for (int s = 0; s < 4; ++s) {
          bf16x8 ak = *(const bf16x8*)(kbase + rb + ((s * 32 + hi * 16) ^ swz));
          st1 = __builtin_amdgcn_mfma_f32_32x32x16_bf16(ak, aq[s], st1, 0, 0, 0);
        }
      }

      if (k0 + 31 > qrow0) {
#pragma unroll
        for (int r = 0; r < 16; ++r) {
          int kk = k0 + (r & 3) + 8 * (r >> 2) + 4 * hi;
          if (kk > qg) st0[r] = -INFINITY;
        }
      }
      if (k0 + 63 > qrow0) {
#pragma unroll
        for (int r = 0; r < 16; ++r) {
          int kk = k0 + 32 + (r & 3) + 8 * (r >> 2) + 4 * hi;
          if (kk > qg) st1[r] = -INFINITY;
        }
      }

      // max tree (depth 5)
      float mx[16];
#pragma unroll
      for (int r = 0; r < 16; ++r) mx[r] = fmaxf(st0[r], st1[r]);
#pragma unroll
      for (int r = 0; r < 8; ++r) mx[r] = fmaxf(mx[r], mx[r + 8]);
#pragma unroll
      for (int r = 0; r < 4; ++r) mx[r] = fmaxf(mx[r], mx[r + 4]);
      float pmax = fmaxf(fmaxf(mx[0], mx[1]), fmaxf(mx[2], mx[3]));
      pmax = fmaxf(pmax, __shfl_xor(pmax, 32));

      if (pmax > mr + THR) {  // T13 defer-max
        float alpha = exp2f(mr - pmax);
        mr = pmax;
        lsum *= alpha;
#pragma unroll
        for (int r = 0; r < 16; ++r) { o_lo[r] *= alpha; o_hi[r] *= alpha; }
      }

#pragma unroll
      for (int r = 0; r < 16; ++r) st0[r] = exp2f(st0[r] - mr);
#pragma unroll
      for (int r = 0; r < 16; ++r) st1[r] = exp2f(st1[r] - mr);
      // sum tree
      float sm[16];
#pragma unroll
      for (int r = 0; r < 16; ++r) sm[r] = st0[r] + st1[r];
#pragma unroll
      for (int r = 0; r < 8; ++r) sm[r] += sm[r + 8];
#pragma unroll
      for (int r = 0; r < 4; ++r) sm[r] += sm[r + 4];
      lsum += (sm[0] + sm[1]) + (sm[2] + sm[3]);

      // T12 pack: P -> bf16 A-fragments (st regs die here)
      uint32_t a0, a2, b1, b3, c0, c2, d1, d3;
      swap32(pk2n(st0[0], st0[1]),   pk2n(st0[4], st0[5]),   hi, a0, a2);
      swap32(pk2n(st0[2], st0[3]),   pk2n(st0[6], st0[7]),   hi, b1, b3);
      swap32(pk2n(st0[8], st0[9]),   pk2n(st0[12], st0[13]), hi, c0, c2);
      swap32(pk2n(st0[10], st0[11]), pk2n(st0[14], st0[15]), hi, d1, d3);
      i32x4 u0 = {(int)a0, (int)b1, (int)a2, (int)b3};
      i32x4 u1 = {(int)c0, (int)d1, (int)c2, (int)d3};
      swap32(pk2n(st1[0], st1[1]),   pk2n(st1[4], st1[5]),   hi, a0, a2);
      swap32(pk2n(st1[2], st1[3]),   pk2n(st1[6], st1[7]),   hi, b1, b3);
      swap32(pk2n(st1[8], st1[9]),   pk2n(st1[12], st1[13]), hi, c0, c2);
      swap32(pk2n(st1[10], st1[11]), pk2n(st1[14], st1[15]), hi, d1, d3);
      i32x4 u2 = {(int)a0, (int)b1, (int)a2, (int)b3};
      i32x4 u3 = {(int)c0, (int)d1, (int)c2, (int)d3};
      bf16x8 pa0 = __builtin_bit_cast(bf16x8, u0);
      bf16x8 pa1 = __builtin_bit_cast(bf16x8, u1);
      bf16x8 pa2 = __builtin_bit_cast(bf16x8, u2);
      bf16x8 pa3 = __builtin_bit_cast(bf16x8, u3);

      // PV from swizzled V^T in LDS
      int rlo = l31 * 128, rhi = (l31 + 32) * 128;
      bf16x8 av;
      av = *(const bf16x8*)(vbase + rlo + ((hi * 16) ^ swz));
      o_lo = __builtin_amdgcn_mfma_f32_32x32x16_bf16(av, pa0, o_lo, 0, 0, 0);
      av = *(const bf16x8*)(vbase + rhi + ((hi * 16) ^ swz));
      o_hi = __builtin_amdgcn_mfma_f32_32x32x16_bf16(av, pa0, o_hi, 0, 0, 0);
      av = *(const bf16x8*)(vbase + rlo + ((32 + hi * 16) ^ swz));
      o_lo = __builtin_amdgcn_mfma_f32_32x32x16_bf16(av, pa1, o_lo, 0, 0, 0);
      av = *(const bf16x8*)(vbase + rhi + ((32 + hi * 16) ^ swz));
      o_hi = __builtin_amdgcn_mfma_f32_32x32x16_bf16(av, pa1, o_hi, 0, 0, 0);
      av = *(const bf16x8*)(vbase + rlo + ((64 + hi * 16) ^ swz));
      o_lo = __builtin_amdgcn_mfma_f32_32x32x16_bf16(av, pa2, o_lo, 0, 0, 0);
      av = *(const bf16x8*)(vbase + rhi + ((64 + hi * 16) ^ swz));
      o_hi = __builtin_amdgcn_mfma_f32_32x32x16_bf16(av, pa2, o_hi, 0, 0, 0);
      av = *(const bf16x8*)(vbase + rlo + ((96 + hi * 16) ^ swz));
      o_lo = __builtin_amdgcn_mfma_f32_32x32x16_bf16(av, pa3, o_lo, 0, 0, 0);
      av = *(const bf16x8*)(vbase + rhi + ((96 + hi * 16) ^ swz));
      o_hi = __builtin_amdgcn_mfma_f32_32x32x16_bf16(av, pa3, o_hi, 0, 0, 0);
    }
    __syncthreads();  // drains vmcnt (stage writes) + protects buffer reuse
  }

  lsum += __shfl_xor(lsum, 32);
  float inv = 1.0f / lsum;
  short* obase = ob + (size_t)(b * 2048 + qg) * 1024 + h * 64;
#pragma unroll
  for (int g = 0; g < 4; ++g) {
    int d0 = 8 * g + 4 * hi;
    s16x4 v0, v1;
#pragma unroll
    for (int j = 0; j < 4; ++j) {
      v0[j] = f2bfn(o_lo[4 * g + j] * inv);
      v1[j] = f2bfn(o_hi[4 * g + j] * inv);
    }
    *(s16x4*)(obase + d0) = v0;
    *(s16x4*)(obase + 32 + d0) = v1;
  }
}

extern "C" void kernel_launch(void* const* d_in, const int* in_sizes, int n_in,
                              void* d_out, int out_size, void* d_ws, size_t ws_size,
                              hipStream_t stream) {
  const float* x  = (const float*)d_in[0];
  const float* Wk = (const float*)d_in[1];
  const float* Wq = (const float*)d_in[2];
  const float* Wv = (const float*)d_in[3];
  const float* Wu = (const float*)d_in[4];
  const float* bu = (const float*)d_in[5];
  float* out = (float*)d_out;

  char* ws = (char*)d_ws;
  const size_t MB = 1u << 20;
  short* xb  = (short*)(ws + 0 * MB);
  short* qb  = (short*)(ws + 16 * MB);
  short* kb  = (short*)(ws + 32 * MB);
  short* vb  = (short*)(ws + 48 * MB);
  short* vtb = (short*)(ws + 64 * MB);
  short* ob  = (short*)(ws + 80 * MB);
  short* wqb = (short*)(ws + 96 * MB);
  short* wkb = (short*)(ws + 98 * MB);
  short* wvb = (short*)(ws + 100 * MB);
  short* wub = (short*)(ws + 102 * MB);

  cast_kernel<<<4096, 256, 0, stream>>>(x, xb, 8388608);
  cast4_kernel<<<dim3(512, 4), 256, 0, stream>>>(Wq, Wk, Wv, Wu, wqb, wkb, wvb, wub);

  gemm_qkv_kernel<<<dim3(64, 8, 3), 256, 0, stream>>>(xb, wqb, wkb, wvb, qb, kb, vb);
  transpose_v_kernel<<<dim3(32, 64), 256, 0, stream>>>(vb, vtb);
  attn_kernel<<<512, 512, 0, stream>>>(qb, kb, vtb, ob);
  gemm_out_kernel<<<dim3(64, 8), 256, 0, stream>>>(ob, wub, bu, out);
}